// Round 8
// baseline (418.906 us; speedup 1.0000x reference)
//
#include <hip/hip_runtime.h>
#include <hip/hip_bf16.h>

#define B_ 32
#define T_ 2048
#define D_ 1024
#define N_ 1024
#define M_ (B_*T_)

#define BM 128
#define BN 128
#define BK 64

typedef short bf16x8 __attribute__((ext_vector_type(8)));
typedef float f32x4 __attribute__((ext_vector_type(4)));
typedef unsigned short us4 __attribute__((ext_vector_type(4)));

__device__ __forceinline__ unsigned short bf16_rn(float x) {
    unsigned u = __float_as_uint(x);
    u += 0x7FFFu + ((u >> 16) & 1u);
    return (unsigned short)(u >> 16);
}

__device__ __forceinline__ void gload_lds16(const void* g, void* l) {
    __builtin_amdgcn_global_load_lds(
        (__attribute__((address_space(1))) void*)(g),
        (__attribute__((address_space(3))) void*)(l), 16, 0, 0);
}

// K0: W2 [D][N] fp32 -> W2T bf16 (RTN) [N][D]
__global__ void k0_w2t(const float* __restrict__ W2,
                       unsigned short* __restrict__ Th) {
    __shared__ float tile[32][33];
    int n0 = blockIdx.x * 32, d0 = blockIdx.y * 32;
    int tx = threadIdx.x & 31, ty = threadIdx.x >> 5; // 32 x 8
    #pragma unroll
    for (int i = 0; i < 4; i++) {
        int d = d0 + ty + i * 8;
        tile[ty + i * 8][tx] = W2[d * N_ + n0 + tx];
    }
    __syncthreads();
    #pragma unroll
    for (int i = 0; i < 4; i++) {
        int n = n0 + ty + i * 8;
        Th[n * D_ + d0 + tx] = bf16_rn(tile[tx][ty + i * 8]);
    }
}

// K1: q_proj[b][n] = query[b]@W1[:,n] + b1[n]   (fp32)
__global__ void k1_qproj(const float* __restrict__ query,
                         const float* __restrict__ W1,
                         const float* __restrict__ b1,
                         float* __restrict__ qp) {
    int b = blockIdx.x;
    int n = blockIdx.y * 256 + threadIdx.x;
    const float* q = query + b * D_;
    const float* w = W1 + n;
    float s = 0.f;
    #pragma unroll 8
    for (int d = 0; d < D_; d++) s += q[d] * w[d * N_];
    qp[b * N_ + n] = s + b1[n];
}

// K2: fused score GEMM: score[m] = bV + sum_n V[n]*tanh(qp[b][n]+b2[n]+ values[m]@W2[:,n])
// Single-bf16 A x single-bf16 B (RTN both; absmax 4.88e-4 measured R7, 4.2x
// margin). m97-shape structure (R2/R6-verified): 128x128x64 tiles, 4 waves
// (2x2), 16x16x32 frags, 2 barriers/K-step, 16KB A + 16KB B staged per step
// via global_load_lds (pre-swizzled sources), 32 MFMA/wave/step. nt-pass 0
// converts A fp32->bf16 and caches to ws; passes 1..7 stage A via gload_lds.
template<bool USE_WS_A>
__global__ __launch_bounds__(256, 2) void k2_score(
    const float* __restrict__ values,
    const unsigned short* __restrict__ W2Th,
    const float* __restrict__ qp,
    const float* __restrict__ b2,
    const float* __restrict__ V,
    const float* __restrict__ bV,
    float* __restrict__ score,
    unsigned short* __restrict__ Ah) {
    __shared__ unsigned short sAh[BM * BK];   // 16 KB
    __shared__ unsigned short sBh[BN * BK];   // 16 KB
    __shared__ float red[2 * BM];

    const int tid = threadIdx.x;
    const int lane = tid & 63;
    const int wid = tid >> 6;
    const int wm = wid >> 1, wn = wid & 1;    // wave tile 64x64
    const int g = lane >> 4, c16 = lane & 15;

    const int m0 = blockIdx.x * BM;
    const int b = m0 >> 11; // m0 / T_

    // A reg-staging mapping (pass 0): 16 float4-cols x 16 rows per pass, 8 passes
    const int a_c4 = tid & 15;
    const int a_r0 = tid >> 4;
    // gload_lds staging mapping (per-wave, 8 rows x 8 chunks per instr)
    const int b_rl = lane >> 3;
    const int b_j = lane & 7;

    float rowpart[16];
    #pragma unroll
    for (int i = 0; i < 16; i++) rowpart[i] = 0.f;

    for (int nt = 0; nt < N_ / BN; nt++) {
        f32x4 acc[4][4];
        #pragma unroll
        for (int mi = 0; mi < 4; mi++)
            #pragma unroll
            for (int ni = 0; ni < 4; ni++) {
                f32x4 z = {0.f, 0.f, 0.f, 0.f};
                acc[mi][ni] = z;
            }

        for (int kt = 0; kt < D_ / BK; kt++) {
            const int k0 = kt * BK;
            __syncthreads(); // previous compute done before LDS overwrite

            // --- B tile: global_load_lds from pre-converted W2T, source pre-swizzled
            #pragma unroll
            for (int i = 0; i < 4; i++) {
                int r = wid * 32 + i * 8 + b_rl;
                int jj = b_j ^ (r & 7);
                size_t soff = (size_t)(nt * BN + r) * D_ + k0 + jj * 8;
                gload_lds16(W2Th + soff, &sBh[(wid * 32 + i * 8) * 64]);
            }

            if (USE_WS_A && nt > 0) {
                // --- A tile from bf16 ws cache, gload_lds, pre-swizzled source
                #pragma unroll
                for (int i = 0; i < 4; i++) {
                    int r = wid * 32 + i * 8 + b_rl;
                    int jj = b_j ^ (r & 7);
                    size_t soff = (size_t)(m0 + r) * D_ + k0 + jj * 8;
                    gload_lds16(Ah + soff, &sAh[(wid * 32 + i * 8) * 64]);
                }
            } else {
                // --- A tile: fp32 -> bf16 (RTN), swizzled ds_write
                const float* abase = values + (size_t)m0 * D_ + k0;
                #pragma unroll
                for (int p = 0; p < 8; p++) {
                    int r = p * 16 + a_r0;
                    float4 v = *(const float4*)(abase + (size_t)r * D_ + a_c4 * 4);
                    float vv[4] = {v.x, v.y, v.z, v.w};
                    us4 hv;
                    #pragma unroll
                    for (int q = 0; q < 4; q++)
                        hv[q] = bf16_rn(vv[q]);
                    int idx = r * 64 + ((((a_c4 >> 1) ^ (r & 7)) << 3) | ((a_c4 & 1) << 2));
                    *(us4*)&sAh[idx] = hv;
                    if (USE_WS_A) {
                        // linear [M][D] store for passes 1..7
                        size_t goff = (size_t)(m0 + r) * D_ + k0 + a_c4 * 4;
                        *(us4*)&Ah[goff] = hv;
                    }
                }
            }

            __syncthreads(); // drains vmcnt (gload_lds/stores) + lgkm (ds_write)

            #pragma unroll
            for (int s = 0; s < 2; s++) {
                bf16x8 aH[4], bH[4];
                #pragma unroll
                for (int mi = 0; mi < 4; mi++) {
                    int r = wm * 64 + mi * 16 + c16;
                    int idx = r * 64 + (((s * 4 + g) ^ (r & 7)) << 3);
                    aH[mi] = *(const bf16x8*)&sAh[idx];
                }
                #pragma unroll
                for (int ni = 0; ni < 4; ni++) {
                    int r = wn * 64 + ni * 16 + c16;
                    int idx = r * 64 + (((s * 4 + g) ^ (r & 7)) << 3);
                    bH[ni] = *(const bf16x8*)&sBh[idx];
                }
                #pragma unroll
                for (int mi = 0; mi < 4; mi++)
                    #pragma unroll
                    for (int ni = 0; ni < 4; ni++)
                        acc[mi][ni] = __builtin_amdgcn_mfma_f32_16x16x32_bf16(aH[mi], bH[ni], acc[mi][ni], 0, 0, 0);
            }
        }

        // --- epilogue: accumulate V[n]*tanh(acc + qp + b2) into row partials
        #pragma unroll
        for (int ni = 0; ni < 4; ni++) {
            int n = nt * BN + wn * 64 + ni * 16 + c16;
            float qv = qp[b * N_ + n] + b2[n];
            float Vv = V[n];
            #pragma unroll
            for (int mi = 0; mi < 4; mi++)
                #pragma unroll
                for (int r = 0; r < 4; r++) {
                    rowpart[mi * 4 + r] += tanhf(acc[mi][ni][r] + qv) * Vv;
                }
        }
    }

    // reduce across the 16 n-lanes of each group
    #pragma unroll
    for (int i = 0; i < 16; i++) {
        float v = rowpart[i];
        v += __shfl_xor(v, 1);
        v += __shfl_xor(v, 2);
        v += __shfl_xor(v, 4);
        v += __shfl_xor(v, 8);
        rowpart[i] = v;
    }
    if (c16 == 0) {
        #pragma unroll
        for (int mi = 0; mi < 4; mi++)
            #pragma unroll
            for (int r = 0; r < 4; r++)
                red[wn * BM + wm * 64 + mi * 16 + g * 4 + r] = rowpart[mi * 4 + r];
    }
    __syncthreads();
    if (tid < BM) {
        score[m0 + tid] = red[tid] + red[BM + tid] + bV[0];
    }
}

// K3: softmax over T per batch, in place
__global__ void k3_softmax(float* __restrict__ sw) {
    int b = blockIdx.x;
    float* row = sw + b * T_;
    int tid = threadIdx.x;
    float v[8];
    float lmax = -1e30f;
    #pragma unroll
    for (int i = 0; i < 8; i++) {
        v[i] = row[tid + i * 256];
        lmax = fmaxf(lmax, v[i]);
    }
    #pragma unroll
    for (int d = 1; d < 64; d <<= 1) lmax = fmaxf(lmax, __shfl_xor(lmax, d));
    __shared__ float sm[4], ss[4];
    if ((tid & 63) == 0) sm[tid >> 6] = lmax;
    __syncthreads();
    lmax = fmaxf(fmaxf(sm[0], sm[1]), fmaxf(sm[2], sm[3]));
    float lsum = 0.f;
    #pragma unroll
    for (int i = 0; i < 8; i++) {
        v[i] = expf(v[i] - lmax);
        lsum += v[i];
    }
    #pragma unroll
    for (int d = 1; d < 64; d <<= 1) lsum += __shfl_xor(lsum, d);
    if ((tid & 63) == 0) ss[tid >> 6] = lsum;
    __syncthreads();
    lsum = ss[0] + ss[1] + ss[2] + ss[3];
    float inv = 1.f / lsum;
    #pragma unroll
    for (int i = 0; i < 8; i++) row[tid + i * 256] = v[i] * inv;
}

// K4: context[b][d] += partial over t-slice (atomic, ctx pre-zeroed)
__global__ void k4_context(const float* __restrict__ values,
                           const float* __restrict__ w,
                           float* __restrict__ ctx) {
    int b = blockIdx.x;
    int dc = blockIdx.y;           // 8 chunks of 128 d
    int tc = blockIdx.z;           // 8 chunks of 256 t
    int d4 = threadIdx.x & 31;
    int th = threadIdx.x >> 5;     // 8 t-slices of 32
    const float* wrow = w + b * T_;
    int d = dc * 128 + d4 * 4;
    const float* vbase = values + (size_t)b * T_ * D_ + d;
    float4 acc = {0.f, 0.f, 0.f, 0.f};
    int t0 = tc * 256 + th * 32;
    for (int t = t0; t < t0 + 32; t++) {
        float wt = wrow[t];
        float4 vv = *(const float4*)(vbase + (size_t)t * D_);
        acc.x += wt * vv.x;
        acc.y += wt * vv.y;
        acc.z += wt * vv.z;
        acc.w += wt * vv.w;
    }
    __shared__ float4 red4[256];
    red4[threadIdx.x] = acc;
    __syncthreads();
    if (th == 0) {
        float4 s = red4[d4];
        #pragma unroll
        for (int i = 1; i < 8; i++) {
            float4 o = red4[i * 32 + d4];
            s.x += o.x; s.y += o.y; s.z += o.z; s.w += o.w;
        }
        atomicAdd(&ctx[b * D_ + d + 0], s.x);
        atomicAdd(&ctx[b * D_ + d + 1], s.y);
        atomicAdd(&ctx[b * D_ + d + 2], s.z);
        atomicAdd(&ctx[b * D_ + d + 3], s.w);
    }
}

extern "C" void kernel_launch(void* const* d_in, const int* in_sizes, int n_in,
                              void* d_out, int out_size, void* d_ws, size_t ws_size,
                              hipStream_t stream) {
    const float* query  = (const float*)d_in[0];
    const float* values = (const float*)d_in[1];
    const float* W1     = (const float*)d_in[2];
    const float* b1     = (const float*)d_in[3];
    const float* W2     = (const float*)d_in[4];
    const float* b2     = (const float*)d_in[5];
    const float* V      = (const float*)d_in[6];
    const float* bV     = (const float*)d_in[7];

    float* ctx = (float*)d_out;                 // [B, D]
    float* weights = (float*)d_out + B_ * D_;   // [B, T]: scores, then softmax in place

    // ws: W2T (2 MB) | q_proj (128 KB) | A_hi (128 MB)
    size_t need_base = (size_t)N_ * D_ * sizeof(unsigned short) + (size_t)B_ * N_ * sizeof(float);
    size_t need_full = need_base + (size_t)M_ * D_ * sizeof(unsigned short);
    if (ws_size < need_base) return;
    unsigned short* Th = (unsigned short*)d_ws;
    float* qp = (float*)(Th + (size_t)N_ * D_);
    unsigned short* Ahi = (unsigned short*)(qp + (size_t)B_ * N_);

    k0_w2t<<<dim3(N_ / 32, D_ / 32), 256, 0, stream>>>(W2, Th);
    k1_qproj<<<dim3(B_, N_ / 256), 256, 0, stream>>>(query, W1, b1, qp);
    if (ws_size >= need_full) {
        k2_score<true><<<M_ / BM, 256, 0, stream>>>(values, Th, qp, b2, V, bV, weights, Ahi);
    } else {
        k2_score<false><<<M_ / BM, 256, 0, stream>>>(values, Th, qp, b2, V, bV, weights, Ahi);
    }
    k3_softmax<<<B_, 256, 0, stream>>>(weights);
    hipMemsetAsync(ctx, 0, (size_t)B_ * D_ * sizeof(float), stream);
    k4_context<<<dim3(B_, 8, 8), 256, 0, stream>>>(values, weights, ctx);
}

// Round 9
// 410.936 us; speedup vs baseline: 1.0194x; 1.0194x over previous
//
#include <hip/hip_runtime.h>
#include <hip/hip_bf16.h>

#define B_ 32
#define T_ 2048
#define D_ 1024
#define N_ 1024
#define M_ (B_*T_)

#define BM 64
#define BN 256
#define BK 64

typedef short bf16x8 __attribute__((ext_vector_type(8)));
typedef float f32x4 __attribute__((ext_vector_type(4)));
typedef unsigned short us4 __attribute__((ext_vector_type(4)));

__device__ __forceinline__ unsigned short bf16_rn(float x) {
    unsigned u = __float_as_uint(x);
    u += 0x7FFFu + ((u >> 16) & 1u);
    return (unsigned short)(u >> 16);
}

__device__ __forceinline__ void gload_lds16(const void* g, void* l) {
    __builtin_amdgcn_global_load_lds(
        (__attribute__((address_space(1))) void*)(g),
        (__attribute__((address_space(3))) void*)(l), 16, 0, 0);
}

// K0: W2 [D][N] fp32 -> W2T bf16 (RTN) [N][D]
__global__ void k0_w2t(const float* __restrict__ W2,
                       unsigned short* __restrict__ Th) {
    __shared__ float tile[32][33];
    int n0 = blockIdx.x * 32, d0 = blockIdx.y * 32;
    int tx = threadIdx.x & 31, ty = threadIdx.x >> 5; // 32 x 8
    #pragma unroll
    for (int i = 0; i < 4; i++) {
        int d = d0 + ty + i * 8;
        tile[ty + i * 8][tx] = W2[d * N_ + n0 + tx];
    }
    __syncthreads();
    #pragma unroll
    for (int i = 0; i < 4; i++) {
        int n = n0 + ty + i * 8;
        Th[n * D_ + d0 + tx] = bf16_rn(tile[tx][ty + i * 8]);
    }
}

// K1: q_proj[b][n] = query[b]@W1[:,n] + b1[n]   (fp32)
__global__ void k1_qproj(const float* __restrict__ query,
                         const float* __restrict__ W1,
                         const float* __restrict__ b1,
                         float* __restrict__ qp) {
    int b = blockIdx.x;
    int n = blockIdx.y * 256 + threadIdx.x;
    const float* q = query + b * D_;
    const float* w = W1 + n;
    float s = 0.f;
    #pragma unroll 8
    for (int d = 0; d < D_; d++) s += q[d] * w[d * N_];
    qp[b * N_ + n] = s + b1[n];
}

// K2: fused score GEMM: score[m] = bV + sum_n V[n]*tanh(qp[b][n]+b2[n]+ values[m]@W2[:,n])
// Single-bf16 A x single-bf16 B (RTN; absmax 4.88e-4 measured R7/R8, 4.2x margin).
// Geometry: 64x256x64 tile, 4 waves (1M x 4N, wave tile 64x64), 16x16x32 frags,
// 2 barriers/K-step, 64 steps total (4 nt x 16 kt). LDS exactly 40KB -> 4
// blocks/CU with grid=1024 (the R7/R8 post-mortem lever: steps x latency,
// at max co-residency). Staging via global_load_lds, pre-swizzled sources.
// nt-pass 0 converts A fp32->bf16 and caches to ws; passes 1..3 gload_lds it.
template<bool USE_WS_A>
__global__ __launch_bounds__(256, 2) void k2_score(
    const float* __restrict__ values,
    const unsigned short* __restrict__ W2Th,
    const float* __restrict__ qp,
    const float* __restrict__ b2,
    const float* __restrict__ V,
    const float* __restrict__ bV,
    float* __restrict__ score,
    unsigned short* __restrict__ Ah) {
    __shared__ unsigned short sAh[BM * BK];   // 8 KB
    __shared__ unsigned short sBh[BN * BK];   // 32 KB  (total 40 KB exactly)

    const int tid = threadIdx.x;
    const int lane = tid & 63;
    const int wid = tid >> 6;     // 0..3 = wn (N-wave); all waves span all 64 rows
    const int g = lane >> 4, c16 = lane & 15;

    const int m0 = blockIdx.x * BM;
    const int b = m0 >> 11; // m0 / T_

    // A reg-staging mapping (pass 0): 16 float4-cols x 16 rows per pass, 4 passes
    const int a_c4 = tid & 15;
    const int a_r0 = tid >> 4;
    // gload_lds staging mapping (per-wave, 8 rows x 8 chunks per instr)
    const int b_rl = lane >> 3;
    const int b_j = lane & 7;

    float rowpart[16];
    #pragma unroll
    for (int i = 0; i < 16; i++) rowpart[i] = 0.f;

    for (int nt = 0; nt < N_ / BN; nt++) {
        f32x4 acc[4][4];
        #pragma unroll
        for (int mi = 0; mi < 4; mi++)
            #pragma unroll
            for (int ni = 0; ni < 4; ni++) {
                f32x4 z = {0.f, 0.f, 0.f, 0.f};
                acc[mi][ni] = z;
            }

        for (int kt = 0; kt < D_ / BK; kt++) {
            const int k0 = kt * BK;
            __syncthreads(); // previous compute done before LDS overwrite

            // --- B tile (256 rows): 8 gload_lds/thread, source pre-swizzled
            #pragma unroll
            for (int i = 0; i < 8; i++) {
                int r = wid * 64 + i * 8 + b_rl;
                int jj = b_j ^ (r & 7);
                size_t soff = (size_t)(nt * BN + r) * D_ + k0 + jj * 8;
                gload_lds16(W2Th + soff, &sBh[(wid * 64 + i * 8) * 64]);
            }

            if (USE_WS_A && nt > 0) {
                // --- A tile (64 rows) from bf16 ws cache, 2 gload_lds/thread
                #pragma unroll
                for (int i = 0; i < 2; i++) {
                    int r = wid * 16 + i * 8 + b_rl;
                    int jj = b_j ^ (r & 7);
                    size_t soff = (size_t)(m0 + r) * D_ + k0 + jj * 8;
                    gload_lds16(Ah + soff, &sAh[(wid * 16 + i * 8) * 64]);
                }
            } else {
                // --- A tile: fp32 -> bf16 (RTN), swizzled ds_write
                const float* abase = values + (size_t)m0 * D_ + k0;
                #pragma unroll
                for (int p = 0; p < 4; p++) {
                    int r = p * 16 + a_r0;
                    float4 v = *(const float4*)(abase + (size_t)r * D_ + a_c4 * 4);
                    float vv[4] = {v.x, v.y, v.z, v.w};
                    us4 hv;
                    #pragma unroll
                    for (int q = 0; q < 4; q++)
                        hv[q] = bf16_rn(vv[q]);
                    int idx = r * 64 + ((((a_c4 >> 1) ^ (r & 7)) << 3) | ((a_c4 & 1) << 2));
                    *(us4*)&sAh[idx] = hv;
                    if (USE_WS_A) {
                        // linear [M][D] store for passes 1..3
                        size_t goff = (size_t)(m0 + r) * D_ + k0 + a_c4 * 4;
                        *(us4*)&Ah[goff] = hv;
                    }
                }
            }

            __syncthreads(); // drains vmcnt (gload_lds/stores) + lgkm (ds_write)

            #pragma unroll
            for (int s = 0; s < 2; s++) {
                bf16x8 aH[4], bH[4];
                #pragma unroll
                for (int mi = 0; mi < 4; mi++) {
                    int r = mi * 16 + c16;
                    int idx = r * 64 + (((s * 4 + g) ^ (r & 7)) << 3);
                    aH[mi] = *(const bf16x8*)&sAh[idx];
                }
                #pragma unroll
                for (int ni = 0; ni < 4; ni++) {
                    int r = wid * 64 + ni * 16 + c16;
                    int idx = r * 64 + (((s * 4 + g) ^ (r & 7)) << 3);
                    bH[ni] = *(const bf16x8*)&sBh[idx];
                }
                #pragma unroll
                for (int mi = 0; mi < 4; mi++)
                    #pragma unroll
                    for (int ni = 0; ni < 4; ni++)
                        acc[mi][ni] = __builtin_amdgcn_mfma_f32_16x16x32_bf16(aH[mi], bH[ni], acc[mi][ni], 0, 0, 0);
            }
        }

        // --- epilogue: accumulate V[n]*tanh(acc + qp + b2) into row partials
        #pragma unroll
        for (int ni = 0; ni < 4; ni++) {
            int n = nt * BN + wid * 64 + ni * 16 + c16;
            float qv = qp[b * N_ + n] + b2[n];
            float Vv = V[n];
            #pragma unroll
            for (int mi = 0; mi < 4; mi++)
                #pragma unroll
                for (int r = 0; r < 4; r++) {
                    rowpart[mi * 4 + r] += tanhf(acc[mi][ni][r] + qv) * Vv;
                }
        }
    }

    // reduce across the 16 n-lanes of each group
    #pragma unroll
    for (int i = 0; i < 16; i++) {
        float v = rowpart[i];
        v += __shfl_xor(v, 1);
        v += __shfl_xor(v, 2);
        v += __shfl_xor(v, 4);
        v += __shfl_xor(v, 8);
        rowpart[i] = v;
    }
    __syncthreads();               // all MFMA LDS reads done before aliasing sAh
    float* red = (float*)sAh;      // 4*BM floats = 1 KB, aliases A buffer
    if (c16 == 0) {
        #pragma unroll
        for (int mi = 0; mi < 4; mi++)
            #pragma unroll
            for (int r = 0; r < 4; r++)
                red[wid * BM + mi * 16 + g * 4 + r] = rowpart[mi * 4 + r];
    }
    __syncthreads();
    if (tid < BM) {
        score[m0 + tid] = red[tid] + red[BM + tid] + red[2 * BM + tid] + red[3 * BM + tid] + bV[0];
    }
}

// K3: softmax over T per batch, in place
__global__ void k3_softmax(float* __restrict__ sw) {
    int b = blockIdx.x;
    float* row = sw + b * T_;
    int tid = threadIdx.x;
    float v[8];
    float lmax = -1e30f;
    #pragma unroll
    for (int i = 0; i < 8; i++) {
        v[i] = row[tid + i * 256];
        lmax = fmaxf(lmax, v[i]);
    }
    #pragma unroll
    for (int d = 1; d < 64; d <<= 1) lmax = fmaxf(lmax, __shfl_xor(lmax, d));
    __shared__ float sm[4], ss[4];
    if ((tid & 63) == 0) sm[tid >> 6] = lmax;
    __syncthreads();
    lmax = fmaxf(fmaxf(sm[0], sm[1]), fmaxf(sm[2], sm[3]));
    float lsum = 0.f;
    #pragma unroll
    for (int i = 0; i < 8; i++) {
        v[i] = expf(v[i] - lmax);
        lsum += v[i];
    }
    #pragma unroll
    for (int d = 1; d < 64; d <<= 1) lsum += __shfl_xor(lsum, d);
    if ((tid & 63) == 0) ss[tid >> 6] = lsum;
    __syncthreads();
    lsum = ss[0] + ss[1] + ss[2] + ss[3];
    float inv = 1.f / lsum;
    #pragma unroll
    for (int i = 0; i < 8; i++) row[tid + i * 256] = v[i] * inv;
}

// K4: context[b][d] += partial over t-slice (atomic, ctx pre-zeroed)
__global__ void k4_context(const float* __restrict__ values,
                           const float* __restrict__ w,
                           float* __restrict__ ctx) {
    int b = blockIdx.x;
    int dc = blockIdx.y;           // 8 chunks of 128 d
    int tc = blockIdx.z;           // 8 chunks of 256 t
    int d4 = threadIdx.x & 31;
    int th = threadIdx.x >> 5;     // 8 t-slices of 32
    const float* wrow = w + b * T_;
    int d = dc * 128 + d4 * 4;
    const float* vbase = values + (size_t)b * T_ * D_ + d;
    float4 acc = {0.f, 0.f, 0.f, 0.f};
    int t0 = tc * 256 + th * 32;
    for (int t = t0; t < t0 + 32; t++) {
        float wt = wrow[t];
        float4 vv = *(const float4*)(vbase + (size_t)t * D_);
        acc.x += wt * vv.x;
        acc.y += wt * vv.y;
        acc.z += wt * vv.z;
        acc.w += wt * vv.w;
    }
    __shared__ float4 red4[256];
    red4[threadIdx.x] = acc;
    __syncthreads();
    if (th == 0) {
        float4 s = red4[d4];
        #pragma unroll
        for (int i = 1; i < 8; i++) {
            float4 o = red4[i * 32 + d4];
            s.x += o.x; s.y += o.y; s.z += o.z; s.w += o.w;
        }
        atomicAdd(&ctx[b * D_ + d + 0], s.x);
        atomicAdd(&ctx[b * D_ + d + 1], s.y);
        atomicAdd(&ctx[b * D_ + d + 2], s.z);
        atomicAdd(&ctx[b * D_ + d + 3], s.w);
    }
}

extern "C" void kernel_launch(void* const* d_in, const int* in_sizes, int n_in,
                              void* d_out, int out_size, void* d_ws, size_t ws_size,
                              hipStream_t stream) {
    const float* query  = (const float*)d_in[0];
    const float* values = (const float*)d_in[1];
    const float* W1     = (const float*)d_in[2];
    const float* b1     = (const float*)d_in[3];
    const float* W2     = (const float*)d_in[4];
    const float* b2     = (const float*)d_in[5];
    const float* V      = (const float*)d_in[6];
    const float* bV     = (const float*)d_in[7];

    float* ctx = (float*)d_out;                 // [B, D]
    float* weights = (float*)d_out + B_ * D_;   // [B, T]: scores, then softmax in place

    // ws: W2T (2 MB) | q_proj (128 KB) | A_hi (128 MB)
    size_t need_base = (size_t)N_ * D_ * sizeof(unsigned short) + (size_t)B_ * N_ * sizeof(float);
    size_t need_full = need_base + (size_t)M_ * D_ * sizeof(unsigned short);
    if (ws_size < need_base) return;
    unsigned short* Th = (unsigned short*)d_ws;
    float* qp = (float*)(Th + (size_t)N_ * D_);
    unsigned short* Ahi = (unsigned short*)(qp + (size_t)B_ * N_);

    k0_w2t<<<dim3(N_ / 32, D_ / 32), 256, 0, stream>>>(W2, Th);
    k1_qproj<<<dim3(B_, N_ / 256), 256, 0, stream>>>(query, W1, b1, qp);
    if (ws_size >= need_full) {
        k2_score<true><<<M_ / BM, 256, 0, stream>>>(values, Th, qp, b2, V, bV, weights, Ahi);
    } else {
        k2_score<false><<<M_ / BM, 256, 0, stream>>>(values, Th, qp, b2, V, bV, weights, Ahi);
    }
    k3_softmax<<<B_, 256, 0, stream>>>(weights);
    hipMemsetAsync(ctx, 0, (size_t)B_ * D_ * sizeof(float), stream);
    k4_context<<<dim3(B_, 8, 8), 256, 0, stream>>>(values, weights, ctx);
}

// Round 10
// 387.935 us; speedup vs baseline: 1.0798x; 1.0593x over previous
//
#include <hip/hip_runtime.h>
#include <hip/hip_bf16.h>

#define B_ 32
#define T_ 2048
#define D_ 1024
#define N_ 1024
#define M_ (B_*T_)

#define BM 64
#define BN 128
#define BK 64
#define NTSPLIT 2   // grid.y: each block handles 4 of the 8 nt-passes

typedef short bf16x8 __attribute__((ext_vector_type(8)));
typedef float f32x4 __attribute__((ext_vector_type(4)));
typedef unsigned short us4 __attribute__((ext_vector_type(4)));

__device__ __forceinline__ unsigned short bf16_rn(float x) {
    unsigned u = __float_as_uint(x);
    u += 0x7FFFu + ((u >> 16) & 1u);
    return (unsigned short)(u >> 16);
}

__device__ __forceinline__ void gload_lds16(const void* g, void* l) {
    __builtin_amdgcn_global_load_lds(
        (__attribute__((address_space(1))) void*)(g),
        (__attribute__((address_space(3))) void*)(l), 16, 0, 0);
}

// K0: W2 [D][N] fp32 -> W2T bf16 (RTN) [N][D]
__global__ void k0_w2t(const float* __restrict__ W2,
                       unsigned short* __restrict__ Th) {
    __shared__ float tile[32][33];
    int n0 = blockIdx.x * 32, d0 = blockIdx.y * 32;
    int tx = threadIdx.x & 31, ty = threadIdx.x >> 5; // 32 x 8
    #pragma unroll
    for (int i = 0; i < 4; i++) {
        int d = d0 + ty + i * 8;
        tile[ty + i * 8][tx] = W2[d * N_ + n0 + tx];
    }
    __syncthreads();
    #pragma unroll
    for (int i = 0; i < 4; i++) {
        int n = n0 + ty + i * 8;
        Th[n * D_ + d0 + tx] = bf16_rn(tile[tx][ty + i * 8]);
    }
}

// K0v: values [M][D] fp32 -> Av bf16 (RTN), vectorized grid-stride
__global__ void k0_vals(const float* __restrict__ v,
                        unsigned short* __restrict__ o) {
    size_t i = ((size_t)blockIdx.x * 256 + threadIdx.x) * 8;
    const size_t stride = (size_t)gridDim.x * 256 * 8;
    for (; i < (size_t)M_ * D_; i += stride) {
        float4 a = *(const float4*)(v + i);
        float4 b = *(const float4*)(v + i + 4);
        us4 h0, h1;
        h0[0] = bf16_rn(a.x); h0[1] = bf16_rn(a.y);
        h0[2] = bf16_rn(a.z); h0[3] = bf16_rn(a.w);
        h1[0] = bf16_rn(b.x); h1[1] = bf16_rn(b.y);
        h1[2] = bf16_rn(b.z); h1[3] = bf16_rn(b.w);
        *(us4*)(o + i) = h0;
        *(us4*)(o + i + 4) = h1;
    }
}

// K1: q_proj[b][n] = query[b]@W1[:,n] + b1[n]   (fp32)
__global__ void k1_qproj(const float* __restrict__ query,
                         const float* __restrict__ W1,
                         const float* __restrict__ b1,
                         float* __restrict__ qp) {
    int b = blockIdx.x;
    int n = blockIdx.y * 256 + threadIdx.x;
    const float* q = query + b * D_;
    const float* w = W1 + n;
    float s = 0.f;
    #pragma unroll 8
    for (int d = 0; d < D_; d++) s += q[d] * w[d * N_];
    qp[b * N_ + n] = s + b1[n];
}

// K2: fused score GEMM partial: score[m] += sum_{n in my nt range} V[n]*tanh(qp+b2+ values[m]@W2[:,n])
// (bV dropped: softmax is shift-invariant, so bV affects neither output.)
// R7-verified geometry: 64x128x64 tile, 4 waves (2M x 2N, wave tile 32x64),
// acc[2][4] = 32 AGPR (total regs ~96 -> 5 waves/SIMD). 2 barriers/K-step,
// ALL staging uniform via global_load_lds from pre-converted bf16 (A from Av,
// B from W2T), pre-swizzled sources. grid (1024, 2): each block runs 4 nt x
// 16 kt = 64 steps; ~5 blocks/CU co-resident hide each other's staging drain.
__global__ __launch_bounds__(256, 2) void k2_score(
    const unsigned short* __restrict__ Av,
    const unsigned short* __restrict__ W2Th,
    const float* __restrict__ qp,
    const float* __restrict__ b2,
    const float* __restrict__ V,
    float* __restrict__ score) {
    __shared__ unsigned short sAh[BM * BK];   // 8 KB
    __shared__ unsigned short sBh[BN * BK];   // 16 KB
    __shared__ float red[2 * BM];

    const int tid = threadIdx.x;
    const int lane = tid & 63;
    const int wid = tid >> 6;
    const int wm = wid >> 1, wn = wid & 1;    // wave tile 32x64
    const int g = lane >> 4, c16 = lane & 15;

    const int m0 = blockIdx.x * BM;
    const int b = m0 >> 11; // m0 / T_
    const int nt0 = blockIdx.y * (N_ / BN / NTSPLIT);

    // gload_lds staging mapping (per-wave, 8 rows x 8 chunks per instr)
    const int b_rl = lane >> 3;
    const int b_j = lane & 7;

    float rowpart[8];
    #pragma unroll
    for (int i = 0; i < 8; i++) rowpart[i] = 0.f;

    for (int nt = nt0; nt < nt0 + N_ / BN / NTSPLIT; nt++) {
        f32x4 acc[2][4];
        #pragma unroll
        for (int mi = 0; mi < 2; mi++)
            #pragma unroll
            for (int ni = 0; ni < 4; ni++) {
                f32x4 z = {0.f, 0.f, 0.f, 0.f};
                acc[mi][ni] = z;
            }

        for (int kt = 0; kt < D_ / BK; kt++) {
            const int k0 = kt * BK;
            __syncthreads(); // previous compute done before LDS overwrite

            // --- B tile: 4 gload_lds/thread from W2T, source pre-swizzled
            #pragma unroll
            for (int i = 0; i < 4; i++) {
                int r = wid * 32 + i * 8 + b_rl;
                int jj = b_j ^ (r & 7);
                size_t soff = (size_t)(nt * BN + r) * D_ + k0 + jj * 8;
                gload_lds16(W2Th + soff, &sBh[(wid * 32 + i * 8) * 64]);
            }
            // --- A tile: 2 gload_lds/thread from Av, source pre-swizzled
            #pragma unroll
            for (int i = 0; i < 2; i++) {
                int r = wid * 16 + i * 8 + b_rl;
                int jj = b_j ^ (r & 7);
                size_t soff = (size_t)(m0 + r) * D_ + k0 + jj * 8;
                gload_lds16(Av + soff, &sAh[(wid * 16 + i * 8) * 64]);
            }

            __syncthreads(); // drains vmcnt (gload_lds)

            #pragma unroll
            for (int s = 0; s < 2; s++) {
                bf16x8 aH[2], bH[4];
                #pragma unroll
                for (int mi = 0; mi < 2; mi++) {
                    int r = wm * 32 + mi * 16 + c16;
                    int idx = r * 64 + (((s * 4 + g) ^ (r & 7)) << 3);
                    aH[mi] = *(const bf16x8*)&sAh[idx];
                }
                #pragma unroll
                for (int ni = 0; ni < 4; ni++) {
                    int r = wn * 64 + ni * 16 + c16;
                    int idx = r * 64 + (((s * 4 + g) ^ (r & 7)) << 3);
                    bH[ni] = *(const bf16x8*)&sBh[idx];
                }
                #pragma unroll
                for (int mi = 0; mi < 2; mi++)
                    #pragma unroll
                    for (int ni = 0; ni < 4; ni++)
                        acc[mi][ni] = __builtin_amdgcn_mfma_f32_16x16x32_bf16(aH[mi], bH[ni], acc[mi][ni], 0, 0, 0);
            }
        }

        // --- epilogue: accumulate V[n]*tanh(acc + qp + b2) into row partials
        #pragma unroll
        for (int ni = 0; ni < 4; ni++) {
            int n = nt * BN + wn * 64 + ni * 16 + c16;
            float qv = qp[b * N_ + n] + b2[n];
            float Vv = V[n];
            #pragma unroll
            for (int mi = 0; mi < 2; mi++)
                #pragma unroll
                for (int r = 0; r < 4; r++) {
                    rowpart[mi * 4 + r] += tanhf(acc[mi][ni][r] + qv) * Vv;
                }
        }
    }

    // reduce across the 16 n-lanes of each group
    #pragma unroll
    for (int i = 0; i < 8; i++) {
        float v = rowpart[i];
        v += __shfl_xor(v, 1);
        v += __shfl_xor(v, 2);
        v += __shfl_xor(v, 4);
        v += __shfl_xor(v, 8);
        rowpart[i] = v;
    }
    if (c16 == 0) {
        #pragma unroll
        for (int mi = 0; mi < 2; mi++)
            #pragma unroll
            for (int r = 0; r < 4; r++)
                red[wn * BM + wm * 32 + mi * 16 + g * 4 + r] = rowpart[mi * 4 + r];
    }
    __syncthreads();
    if (tid < BM) {
        // two adds per location (grid.y=2), fp-commutative -> deterministic
        atomicAdd(&score[m0 + tid], red[tid] + red[BM + tid]);
    }
}

// K3: softmax over T per batch, in place
__global__ void k3_softmax(float* __restrict__ sw) {
    int b = blockIdx.x;
    float* row = sw + b * T_;
    int tid = threadIdx.x;
    float v[8];
    float lmax = -1e30f;
    #pragma unroll
    for (int i = 0; i < 8; i++) {
        v[i] = row[tid + i * 256];
        lmax = fmaxf(lmax, v[i]);
    }
    #pragma unroll
    for (int d = 1; d < 64; d <<= 1) lmax = fmaxf(lmax, __shfl_xor(lmax, d));
    __shared__ float sm[4], ss[4];
    if ((tid & 63) == 0) sm[tid >> 6] = lmax;
    __syncthreads();
    lmax = fmaxf(fmaxf(sm[0], sm[1]), fmaxf(sm[2], sm[3]));
    float lsum = 0.f;
    #pragma unroll
    for (int i = 0; i < 8; i++) {
        v[i] = expf(v[i] - lmax);
        lsum += v[i];
    }
    #pragma unroll
    for (int d = 1; d < 64; d <<= 1) lsum += __shfl_xor(lsum, d);
    if ((tid & 63) == 0) ss[tid >> 6] = lsum;
    __syncthreads();
    lsum = ss[0] + ss[1] + ss[2] + ss[3];
    float inv = 1.f / lsum;
    #pragma unroll
    for (int i = 0; i < 8; i++) row[tid + i * 256] = v[i] * inv;
}

// K4: context[b][d] += partial over t-slice (atomic, ctx pre-zeroed)
__global__ void k4_context(const float* __restrict__ values,
                           const float* __restrict__ w,
                           float* __restrict__ ctx) {
    int b = blockIdx.x;
    int dc = blockIdx.y;           // 8 chunks of 128 d
    int tc = blockIdx.z;           // 8 chunks of 256 t
    int d4 = threadIdx.x & 31;
    int th = threadIdx.x >> 5;     // 8 t-slices of 32
    const float* wrow = w + b * T_;
    int d = dc * 128 + d4 * 4;
    const float* vbase = values + (size_t)b * T_ * D_ + d;
    float4 acc = {0.f, 0.f, 0.f, 0.f};
    int t0 = tc * 256 + th * 32;
    for (int t = t0; t < t0 + 32; t++) {
        float wt = wrow[t];
        float4 vv = *(const float4*)(vbase + (size_t)t * D_);
        acc.x += wt * vv.x;
        acc.y += wt * vv.y;
        acc.z += wt * vv.z;
        acc.w += wt * vv.w;
    }
    __shared__ float4 red4[256];
    red4[threadIdx.x] = acc;
    __syncthreads();
    if (th == 0) {
        float4 s = red4[d4];
        #pragma unroll
        for (int i = 1; i < 8; i++) {
            float4 o = red4[i * 32 + d4];
            s.x += o.x; s.y += o.y; s.z += o.z; s.w += o.w;
        }
        atomicAdd(&ctx[b * D_ + d + 0], s.x);
        atomicAdd(&ctx[b * D_ + d + 1], s.y);
        atomicAdd(&ctx[b * D_ + d + 2], s.z);
        atomicAdd(&ctx[b * D_ + d + 3], s.w);
    }
}

extern "C" void kernel_launch(void* const* d_in, const int* in_sizes, int n_in,
                              void* d_out, int out_size, void* d_ws, size_t ws_size,
                              hipStream_t stream) {
    const float* query  = (const float*)d_in[0];
    const float* values = (const float*)d_in[1];
    const float* W1     = (const float*)d_in[2];
    const float* b1     = (const float*)d_in[3];
    const float* W2     = (const float*)d_in[4];
    const float* b2     = (const float*)d_in[5];
    const float* V      = (const float*)d_in[6];
    // d_in[7] = bV: unused — softmax is shift-invariant, bV affects neither output.

    float* ctx = (float*)d_out;                 // [B, D]
    float* weights = (float*)d_out + B_ * D_;   // [B, T]: scores, then softmax in place

    // ws: W2T (2 MB) | q_proj (128 KB) | Av bf16 (128 MB)
    size_t need = (size_t)N_ * D_ * sizeof(unsigned short)
                + (size_t)B_ * N_ * sizeof(float)
                + (size_t)M_ * D_ * sizeof(unsigned short);
    if (ws_size < need) return;
    unsigned short* Th = (unsigned short*)d_ws;
    float* qp = (float*)(Th + (size_t)N_ * D_);
    unsigned short* Av = (unsigned short*)(qp + (size_t)B_ * N_);

    k0_w2t<<<dim3(N_ / 32, D_ / 32), 256, 0, stream>>>(W2, Th);
    k0_vals<<<2048, 256, 0, stream>>>(values, Av);
    k1_qproj<<<dim3(B_, N_ / 256), 256, 0, stream>>>(query, W1, b1, qp);
    hipMemsetAsync(weights, 0, (size_t)B_ * T_ * sizeof(float), stream);
    k2_score<<<dim3(M_ / BM, NTSPLIT), 256, 0, stream>>>(Av, Th, qp, b2, V, weights);
    k3_softmax<<<B_, 256, 0, stream>>>(weights);
    hipMemsetAsync(ctx, 0, (size_t)B_ * D_ * sizeof(float), stream);
    k4_context<<<dim3(B_, 8, 8), 256, 0, stream>>>(values, weights, ctx);
}

// Round 11
// 358.556 us; speedup vs baseline: 1.1683x; 1.0819x over previous
//
#include <hip/hip_runtime.h>
#include <hip/hip_bf16.h>

#define B_ 32
#define T_ 2048
#define D_ 1024
#define N_ 1024
#define M_ (B_*T_)

#define BM 64
#define BN 128
#define BK 64
#define NTSPLIT 2   // two score-partials per m0; 2-way atomic sum is order-invariant

typedef short bf16x8 __attribute__((ext_vector_type(8)));
typedef float f32x4 __attribute__((ext_vector_type(4)));
typedef unsigned short us4 __attribute__((ext_vector_type(4)));

__device__ __forceinline__ unsigned short bf16_rn(float x) {
    unsigned u = __float_as_uint(x);
    u += 0x7FFFu + ((u >> 16) & 1u);
    return (unsigned short)(u >> 16);
}

__device__ __forceinline__ void gload_lds16(const void* g, void* l) {
    __builtin_amdgcn_global_load_lds(
        (__attribute__((address_space(1))) void*)(g),
        (__attribute__((address_space(3))) void*)(l), 16, 0, 0);
}

// K0: W2 [D][N] fp32 -> W2T bf16 (RTN) [N][D]
__global__ void k0_w2t(const float* __restrict__ W2,
                       unsigned short* __restrict__ Th) {
    __shared__ float tile[32][33];
    int n0 = blockIdx.x * 32, d0 = blockIdx.y * 32;
    int tx = threadIdx.x & 31, ty = threadIdx.x >> 5; // 32 x 8
    #pragma unroll
    for (int i = 0; i < 4; i++) {
        int d = d0 + ty + i * 8;
        tile[ty + i * 8][tx] = W2[d * N_ + n0 + tx];
    }
    __syncthreads();
    #pragma unroll
    for (int i = 0; i < 4; i++) {
        int n = n0 + ty + i * 8;
        Th[n * D_ + d0 + tx] = bf16_rn(tile[tx][ty + i * 8]);
    }
}

// K0v: values [M][D] fp32 -> Av bf16 (RTN), vectorized grid-stride
__global__ void k0_vals(const float* __restrict__ v,
                        unsigned short* __restrict__ o) {
    size_t i = ((size_t)blockIdx.x * 256 + threadIdx.x) * 8;
    const size_t stride = (size_t)gridDim.x * 256 * 8;
    for (; i < (size_t)M_ * D_; i += stride) {
        float4 a = *(const float4*)(v + i);
        float4 b = *(const float4*)(v + i + 4);
        us4 h0, h1;
        h0[0] = bf16_rn(a.x); h0[1] = bf16_rn(a.y);
        h0[2] = bf16_rn(a.z); h0[3] = bf16_rn(a.w);
        h1[0] = bf16_rn(b.x); h1[1] = bf16_rn(b.y);
        h1[2] = bf16_rn(b.z); h1[3] = bf16_rn(b.w);
        *(us4*)(o + i) = h0;
        *(us4*)(o + i + 4) = h1;
    }
}

// K1: q_proj[b][n] = query[b]@W1[:,n] + b1[n]   (fp32)
__global__ void k1_qproj(const float* __restrict__ query,
                         const float* __restrict__ W1,
                         const float* __restrict__ b1,
                         float* __restrict__ qp) {
    int b = blockIdx.x;
    int n = blockIdx.y * 256 + threadIdx.x;
    const float* q = query + b * D_;
    const float* w = W1 + n;
    float s = 0.f;
    #pragma unroll 8
    for (int d = 0; d < D_; d++) s += q[d] * w[d * N_];
    qp[b * N_ + n] = s + b1[n];
}

// K2: fused score GEMM partial: score[m] += sum_{n in my nt range} V[n]*tanh(qp+b2+ values[m]@W2[:,n])
// (bV dropped: softmax is shift-invariant.) R10-verified: 64x128x64 tile,
// 4 waves (2M x 2N), acc[2][4]=32 AGPR (64 VGPR total, 5 waves/SIMD),
// 2 barriers/K-step, uniform gload_lds staging from pre-converted bf16.
// NEW: 1-D grid 2048 + bijective XCD swizzle (wgid = rot(bid)) so the two
// NTSPLIT replicas of an m0 are bids 8 apart -> same XCD (round-robin model),
// concurrent -> pair shares one L2 fetch of the 128KB A-slice. Heuristic
// only; correctness independent of HW block->XCD mapping.
__global__ __launch_bounds__(256, 2) void k2_score(
    const unsigned short* __restrict__ Av,
    const unsigned short* __restrict__ W2Th,
    const float* __restrict__ qp,
    const float* __restrict__ b2,
    const float* __restrict__ V,
    float* __restrict__ score) {
    __shared__ unsigned short sAh[BM * BK];   // 8 KB
    __shared__ unsigned short sBh[BN * BK];   // 16 KB
    __shared__ float red[2 * BM];

    const int tid = threadIdx.x;
    const int lane = tid & 63;
    const int wid = tid >> 6;
    const int wm = wid >> 1, wn = wid & 1;    // wave tile 32x64
    const int g = lane >> 4, c16 = lane & 15;

    // XCD-pairing swizzle: bid -> wgid (bit rotation, bijective on [0,2048))
    const int bid = blockIdx.x;
    const int wgid = ((bid & 7) << 8) | (bid >> 3);
    const int m0 = (wgid >> 1) * BM;
    const int b = m0 >> 11; // m0 / T_
    const int nt0 = (wgid & 1) * (N_ / BN / NTSPLIT);

    // gload_lds staging mapping (per-wave, 8 rows x 8 chunks per instr)
    const int b_rl = lane >> 3;
    const int b_j = lane & 7;

    float rowpart[8];
    #pragma unroll
    for (int i = 0; i < 8; i++) rowpart[i] = 0.f;

    for (int nt = nt0; nt < nt0 + N_ / BN / NTSPLIT; nt++) {
        f32x4 acc[2][4];
        #pragma unroll
        for (int mi = 0; mi < 2; mi++)
            #pragma unroll
            for (int ni = 0; ni < 4; ni++) {
                f32x4 z = {0.f, 0.f, 0.f, 0.f};
                acc[mi][ni] = z;
            }

        for (int kt = 0; kt < D_ / BK; kt++) {
            const int k0 = kt * BK;
            __syncthreads(); // previous compute done before LDS overwrite

            // --- B tile: 4 gload_lds/thread from W2T, source pre-swizzled
            #pragma unroll
            for (int i = 0; i < 4; i++) {
                int r = wid * 32 + i * 8 + b_rl;
                int jj = b_j ^ (r & 7);
                size_t soff = (size_t)(nt * BN + r) * D_ + k0 + jj * 8;
                gload_lds16(W2Th + soff, &sBh[(wid * 32 + i * 8) * 64]);
            }
            // --- A tile: 2 gload_lds/thread from Av, source pre-swizzled
            #pragma unroll
            for (int i = 0; i < 2; i++) {
                int r = wid * 16 + i * 8 + b_rl;
                int jj = b_j ^ (r & 7);
                size_t soff = (size_t)(m0 + r) * D_ + k0 + jj * 8;
                gload_lds16(Av + soff, &sAh[(wid * 16 + i * 8) * 64]);
            }

            __syncthreads(); // drains vmcnt (gload_lds)

            #pragma unroll
            for (int s = 0; s < 2; s++) {
                bf16x8 aH[2], bH[4];
                #pragma unroll
                for (int mi = 0; mi < 2; mi++) {
                    int r = wm * 32 + mi * 16 + c16;
                    int idx = r * 64 + (((s * 4 + g) ^ (r & 7)) << 3);
                    aH[mi] = *(const bf16x8*)&sAh[idx];
                }
                #pragma unroll
                for (int ni = 0; ni < 4; ni++) {
                    int r = wn * 64 + ni * 16 + c16;
                    int idx = r * 64 + (((s * 4 + g) ^ (r & 7)) << 3);
                    bH[ni] = *(const bf16x8*)&sBh[idx];
                }
                #pragma unroll
                for (int mi = 0; mi < 2; mi++)
                    #pragma unroll
                    for (int ni = 0; ni < 4; ni++)
                        acc[mi][ni] = __builtin_amdgcn_mfma_f32_16x16x32_bf16(aH[mi], bH[ni], acc[mi][ni], 0, 0, 0);
            }
        }

        // --- epilogue: accumulate V[n]*tanh(acc + qp + b2) into row partials
        #pragma unroll
        for (int ni = 0; ni < 4; ni++) {
            int n = nt * BN + wn * 64 + ni * 16 + c16;
            float qv = qp[b * N_ + n] + b2[n];
            float Vv = V[n];
            #pragma unroll
            for (int mi = 0; mi < 2; mi++)
                #pragma unroll
                for (int r = 0; r < 4; r++) {
                    rowpart[mi * 4 + r] += tanhf(acc[mi][ni][r] + qv) * Vv;
                }
        }
    }

    // reduce across the 16 n-lanes of each group
    #pragma unroll
    for (int i = 0; i < 8; i++) {
        float v = rowpart[i];
        v += __shfl_xor(v, 1);
        v += __shfl_xor(v, 2);
        v += __shfl_xor(v, 4);
        v += __shfl_xor(v, 8);
        rowpart[i] = v;
    }
    if (c16 == 0) {
        #pragma unroll
        for (int mi = 0; mi < 2; mi++)
            #pragma unroll
            for (int r = 0; r < 4; r++)
                red[wn * BM + wm * 32 + mi * 16 + g * 4 + r] = rowpart[mi * 4 + r];
    }
    __syncthreads();
    if (tid < BM) {
        // two adds per location (NTSPLIT=2), fp-commutative -> deterministic
        atomicAdd(&score[m0 + tid], red[tid] + red[BM + tid]);
    }
}

// K3: softmax over T per batch, in place
__global__ void k3_softmax(float* __restrict__ sw) {
    int b = blockIdx.x;
    float* row = sw + b * T_;
    int tid = threadIdx.x;
    float v[8];
    float lmax = -1e30f;
    #pragma unroll
    for (int i = 0; i < 8; i++) {
        v[i] = row[tid + i * 256];
        lmax = fmaxf(lmax, v[i]);
    }
    #pragma unroll
    for (int d = 1; d < 64; d <<= 1) lmax = fmaxf(lmax, __shfl_xor(lmax, d));
    __shared__ float sm[4], ss[4];
    if ((tid & 63) == 0) sm[tid >> 6] = lmax;
    __syncthreads();
    lmax = fmaxf(fmaxf(sm[0], sm[1]), fmaxf(sm[2], sm[3]));
    float lsum = 0.f;
    #pragma unroll
    for (int i = 0; i < 8; i++) {
        v[i] = expf(v[i] - lmax);
        lsum += v[i];
    }
    #pragma unroll
    for (int d = 1; d < 64; d <<= 1) lsum += __shfl_xor(lsum, d);
    if ((tid & 63) == 0) ss[tid >> 6] = lsum;
    __syncthreads();
    lsum = ss[0] + ss[1] + ss[2] + ss[3];
    float inv = 1.f / lsum;
    #pragma unroll
    for (int i = 0; i < 8; i++) row[tid + i * 256] = v[i] * inv;
}

// K4: context[b][d] += partial over t-slice, reading bf16 Av (half traffic).
// (atomic, ctx pre-zeroed)
__global__ void k4_context(const unsigned short* __restrict__ Av,
                           const float* __restrict__ w,
                           float* __restrict__ ctx) {
    int b = blockIdx.x;
    int dc = blockIdx.y;           // 8 chunks of 128 d
    int tc = blockIdx.z;           // 8 chunks of 256 t
    int d4 = threadIdx.x & 31;
    int th = threadIdx.x >> 5;     // 8 t-slices of 32
    const float* wrow = w + b * T_;
    int d = dc * 128 + d4 * 4;
    const unsigned short* vbase = Av + (size_t)b * T_ * D_ + d;
    float4 acc = {0.f, 0.f, 0.f, 0.f};
    int t0 = tc * 256 + th * 32;
    for (int t = t0; t < t0 + 32; t++) {
        float wt = wrow[t];
        us4 hv = *(const us4*)(vbase + (size_t)t * D_);
        acc.x += wt * __uint_as_float((unsigned)hv[0] << 16);
        acc.y += wt * __uint_as_float((unsigned)hv[1] << 16);
        acc.z += wt * __uint_as_float((unsigned)hv[2] << 16);
        acc.w += wt * __uint_as_float((unsigned)hv[3] << 16);
    }
    __shared__ float4 red4[256];
    red4[threadIdx.x] = acc;
    __syncthreads();
    if (th == 0) {
        float4 s = red4[d4];
        #pragma unroll
        for (int i = 1; i < 8; i++) {
            float4 o = red4[i * 32 + d4];
            s.x += o.x; s.y += o.y; s.z += o.z; s.w += o.w;
        }
        atomicAdd(&ctx[b * D_ + d + 0], s.x);
        atomicAdd(&ctx[b * D_ + d + 1], s.y);
        atomicAdd(&ctx[b * D_ + d + 2], s.z);
        atomicAdd(&ctx[b * D_ + d + 3], s.w);
    }
}

extern "C" void kernel_launch(void* const* d_in, const int* in_sizes, int n_in,
                              void* d_out, int out_size, void* d_ws, size_t ws_size,
                              hipStream_t stream) {
    const float* query  = (const float*)d_in[0];
    const float* values = (const float*)d_in[1];
    const float* W1     = (const float*)d_in[2];
    const float* b1     = (const float*)d_in[3];
    const float* W2     = (const float*)d_in[4];
    const float* b2     = (const float*)d_in[5];
    const float* V      = (const float*)d_in[6];
    // d_in[7] = bV: unused — softmax is shift-invariant, bV affects neither output.

    float* ctx = (float*)d_out;                 // [B, D]
    float* weights = (float*)d_out + B_ * D_;   // [B, T]: scores, then softmax in place

    // ws: W2T (2 MB) | q_proj (128 KB) | Av bf16 (128 MB)
    size_t need = (size_t)N_ * D_ * sizeof(unsigned short)
                + (size_t)B_ * N_ * sizeof(float)
                + (size_t)M_ * D_ * sizeof(unsigned short);
    if (ws_size < need) return;
    unsigned short* Th = (unsigned short*)d_ws;
    float* qp = (float*)(Th + (size_t)N_ * D_);
    unsigned short* Av = (unsigned short*)(qp + (size_t)B_ * N_);

    k0_w2t<<<dim3(N_ / 32, D_ / 32), 256, 0, stream>>>(W2, Th);
    k0_vals<<<2048, 256, 0, stream>>>(values, Av);
    k1_qproj<<<dim3(B_, N_ / 256), 256, 0, stream>>>(query, W1, b1, qp);
    hipMemsetAsync(weights, 0, (size_t)B_ * T_ * sizeof(float), stream);
    k2_score<<<(M_ / BM) * NTSPLIT, 256, 0, stream>>>(Av, Th, qp, b2, V, weights);
    k3_softmax<<<B_, 256, 0, stream>>>(weights);
    hipMemsetAsync(ctx, 0, (size_t)B_ * D_ * sizeof(float), stream);
    k4_context<<<dim3(B_, 8, 8), 256, 0, stream>>>(Av, weights, ctx);
}